// Round 1
// baseline (590.494 us; speedup 1.0000x reference)
//
#include <hip/hip_runtime.h>
#include <cstdint>
#include <cstddef>

#define B_   2
#define S_   2048
#define H_   16
#define D_   128
#define HID_ 2048

typedef __bf16 bf16;
typedef bf16 bf16x4 __attribute__((ext_vector_type(4)));
typedef bf16 bf16x8 __attribute__((ext_vector_type(8)));
typedef float f32x4 __attribute__((ext_vector_type(4)));

__device__ __forceinline__ f32x4 mfma16(bf16x8 a, bf16x8 b, f32x4 c){
  return __builtin_amdgcn_mfma_f32_16x16x32_bf16(a, b, c, 0, 0, 0);
}

__device__ __forceinline__ void gload_lds16(const void* g, void* l){
  __builtin_amdgcn_global_load_lds((const __attribute__((address_space(1))) void*)g,
                                   (__attribute__((address_space(3))) void*)l, 16, 0, 0);
}

// ---------------- RoPE tables: cos/sin [S][64] fp32 ----------------
__global__ void k_tables(float* __restrict__ cosT, float* __restrict__ sinT){
  int id = blockIdx.x*256 + threadIdx.x;      // S*64 = 131072 exact
  int p = id >> 6, i = id & 63;
  double f = (double)p * pow(10000.0, -(double)i/64.0);
  cosT[id] = (float)cos(f);
  sinT[id] = (float)sin(f);
}

// ---------------- fp32 -> bf16 convert (vec4) ----------------
__global__ void k_cvt(const float* __restrict__ in, bf16* __restrict__ out, int n4){
  int i = blockIdx.x*256 + threadIdx.x;
  if (i >= n4) return;
  f32x4 v = *reinterpret_cast<const f32x4*>(in + (size_t)i*4);
  bf16x4 o;
  o[0]=(bf16)v[0]; o[1]=(bf16)v[1]; o[2]=(bf16)v[2]; o[3]=(bf16)v[3];
  *reinterpret_cast<bf16x4*>(out + (size_t)i*4) = o;
}

// ---------------- hidden [B][S][HID] f32 -> hiddenT [B][HID][S] bf16 ----------------
__global__ __launch_bounds__(256) void k_transpose_cvt(const float* __restrict__ in, bf16* __restrict__ out){
  __shared__ bf16 t[64][72];
  const int tid = threadIdx.x;
  const int b = blockIdx.z, j0 = blockIdx.x*64, s0 = blockIdx.y*64;
  #pragma unroll
  for (int u0 = 0; u0 < 4; ++u0){
    int u = u0*256 + tid;
    int r = u >> 4, c4 = (u & 15)*4;
    f32x4 v = *reinterpret_cast<const f32x4*>(in + ((size_t)b*S_ + s0 + r)*HID_ + j0 + c4);
    bf16x4 o; o[0]=(bf16)v[0]; o[1]=(bf16)v[1]; o[2]=(bf16)v[2]; o[3]=(bf16)v[3];
    *reinterpret_cast<bf16x4*>(&t[r][c4]) = o;
  }
  __syncthreads();
  #pragma unroll
  for (int u0 = 0; u0 < 4; ++u0){
    int u = u0*256 + tid;
    int r = u >> 4, c4 = (u & 15)*4;    // r: j-local, c4: s-local
    bf16x4 o;
    o[0] = t[c4+0][r]; o[1] = t[c4+1][r]; o[2] = t[c4+2][r]; o[3] = t[c4+3][r];
    *reinterpret_cast<bf16x4*>(out + ((size_t)b*HID_ + j0 + r)*S_ + s0 + c4) = o;
  }
}

// ---------------- NT GEMM: C[M,N] = A[M,K] * B[N,K]^T, bf16 in, fp32 acc ----------------
// EPI 0: store bf16.  EPI 1: += (1-mask[row])*hid[row,col], store bf16 (batched, M=S_).  EPI 2: store fp32.
template<int EPI>
__global__ __launch_bounds__(256) void k_gemm_nt(
    const bf16* __restrict__ A, const bf16* __restrict__ Bm, void* __restrict__ Cv,
    int Kd, size_t sAz, size_t sBz, size_t sCz, int N,
    const float* __restrict__ mask, const float* __restrict__ hid)
{
  const int tid = threadIdx.x;
  const int wid = tid >> 6, lane = tid & 63;
  const int g = lane >> 4, li = lane & 15;
  const int z = blockIdx.z;
  const int m0 = blockIdx.y*128, n0 = blockIdx.x*128;
  const int wm = wid >> 1, wn = wid & 1;
  const bf16* Ab = A + (size_t)z*sAz;
  const bf16* Bb = Bm + (size_t)z*sBz;

  __shared__ bf16 lA[128*64];
  __shared__ bf16 lB[128*64];

  f32x4 acc[4][4];
  #pragma unroll
  for (int i=0;i<4;++i)
    #pragma unroll
    for (int j=0;j<4;++j)
      acc[i][j] = {0.f,0.f,0.f,0.f};

  for (int k0 = 0; k0 < Kd; k0 += 64){
    #pragma unroll
    for (int j=0;j<4;++j){
      int ci = j*256 + tid;
      int r = ci >> 3, cb = ci & 7;     // 8 chunks of 16B per 64-elem row
      gload_lds16(Ab + (size_t)(m0 + r)*Kd + k0 + cb*8, (char*)lA + (j*256 + wid*64)*16);
      gload_lds16(Bb + (size_t)(n0 + r)*Kd + k0 + cb*8, (char*)lB + (j*256 + wid*64)*16);
    }
    __syncthreads();
    #pragma unroll
    for (int kk=0;kk<2;++kk){
      bf16x8 af[4], bfm[4];
      #pragma unroll
      for (int i=0;i<4;++i){
        af[i]  = *reinterpret_cast<const bf16x8*>(&lA[(wm*64 + i*16 + li)*64 + kk*32 + g*8]);
        bfm[i] = *reinterpret_cast<const bf16x8*>(&lB[(wn*64 + i*16 + li)*64 + kk*32 + g*8]);
      }
      #pragma unroll
      for (int i=0;i<4;++i)
        #pragma unroll
        for (int j=0;j<4;++j)
          acc[i][j] = mfma16(af[i], bfm[j], acc[i][j]);
    }
    __syncthreads();
  }

  #pragma unroll
  for (int i=0;i<4;++i){
    #pragma unroll
    for (int j=0;j<4;++j){
      #pragma unroll
      for (int v=0;v<4;++v){
        int row = m0 + wm*64 + i*16 + g*4 + v;   // C/D: col=lane&15, row=(lane>>4)*4+reg
        int col = n0 + wn*64 + j*16 + li;
        float x = acc[i][j][v];
        if (EPI == 1){
          x += (1.f - mask[z*S_ + row]) * hid[((size_t)z*S_ + row)*HID_ + col];
          ((bf16*)Cv)[(size_t)z*sCz + (size_t)row*N + col] = (bf16)x;
        } else if (EPI == 0){
          ((bf16*)Cv)[(size_t)row*N + col] = (bf16)x;
        } else {
          ((float*)Cv)[(size_t)row*N + col] = x;
        }
      }
    }
  }
}

// ---------------- RoPE in place on [B,S,H,D] bf16 ----------------
__global__ void k_rope(bf16* __restrict__ X, const float* __restrict__ cosT,
                       const float* __restrict__ sinT, const int* __restrict__ pos){
  int id = blockIdx.x*256 + threadIdx.x;   // B*S*H*16 = 1048576 exact
  int d4 = (id & 15)*4;
  int h  = (id >> 4) & 15;
  int s  = (id >> 8) & 2047;
  int b  = id >> 19;
  int p = pos ? pos[b*S_ + s] : s;
  size_t base = (((size_t)b*S_ + s)*H_ + h)*D_ + d4;
  f32x4 c  = *reinterpret_cast<const f32x4*>(cosT + (size_t)p*64 + d4);
  f32x4 sn = *reinterpret_cast<const f32x4*>(sinT + (size_t)p*64 + d4);
  bf16x4 x1 = *reinterpret_cast<bf16x4*>(X + base);
  bf16x4 x2 = *reinterpret_cast<bf16x4*>(X + base + 64);
  bf16x4 o1, o2;
  #pragma unroll
  for (int i=0;i<4;++i){
    float a = (float)x1[i], bb = (float)x2[i];
    o1[i] = (bf16)(a*c[i] - bb*sn[i]);
    o2[i] = (bf16)(bb*c[i] + a*sn[i]);
  }
  *reinterpret_cast<bf16x4*>(X + base) = o1;
  *reinterpret_cast<bf16x4*>(X + base + 64) = o2;
}

// ---------------- causal flash attention ----------------
// Q,K,V,O: [B,S,H,D] bf16. grid (S/64, B*H), 256 thr (4 waves, 16 q-rows/wave).
__global__ __launch_bounds__(256) void k_flash(const bf16* __restrict__ Q, const bf16* __restrict__ K,
                                               const bf16* __restrict__ V, bf16* __restrict__ O)
{
  const int tid = threadIdx.x;
  const int wid = tid >> 6, lane = tid & 63;
  const int g = lane >> 4, li = lane & 15;
  const int bh = blockIdx.y;
  const int b = bh >> 4, h = bh & 15;
  const int qb = blockIdx.x * 64;

  __shared__ bf16 Klds[64*128];     // linear, source chunk-swizzled
  __shared__ bf16 Vt[128*72];       // V transposed [d][kv], padded
  __shared__ bf16 Plds[4][16*72];   // per-wave P

  const int qrow = qb + wid*16 + li;
  const bf16* Qp = Q + (((size_t)b*S_ + qrow)*H_ + h)*D_;
  bf16x8 qf[4];
  #pragma unroll
  for (int kc=0;kc<4;++kc)
    qf[kc] = *reinterpret_cast<const bf16x8*>(Qp + kc*32 + g*8);

  float mrun[4], lrun[4];
  f32x4 acc[8];
  #pragma unroll
  for (int v=0;v<4;++v){ mrun[v] = -1e30f; lrun[v] = 0.f; }
  #pragma unroll
  for (int fn=0;fn<8;++fn) acc[fn] = {0.f,0.f,0.f,0.f};

  const int nt = blockIdx.x + 1;
  for (int t=0; t<nt; ++t){
    const int c0 = t*64;
    // stage K tile [64][128]: 16 chunks of 16B per row, chunk-XOR swizzled source
    #pragma unroll
    for (int j=0;j<4;++j){
      int ci = j*256 + tid;
      int r = ci >> 4, cb = ci & 15;
      const char* src = (const char*)(K + (((size_t)b*S_ + c0 + r)*H_ + h)*D_) + ((cb ^ (r & 7)) * 16);
      gload_lds16(src, (char*)Klds + (j*256 + wid*64)*16);
    }
    // stage V transposed: Vt[d][kv]
    #pragma unroll
    for (int j=0;j<2;++j){
      int u = j*256 + tid;
      int dc = u & 15, kvp = u >> 4;
      const bf16* vsrc = V + (((size_t)b*S_ + c0 + kvp*2)*H_ + h)*D_ + dc*8;
      bf16x8 r0 = *reinterpret_cast<const bf16x8*>(vsrc);
      bf16x8 r1 = *reinterpret_cast<const bf16x8*>(vsrc + H_*D_);
      #pragma unroll
      for (int e=0;e<8;++e){
        bf16* dst = &Vt[(dc*8 + e)*72 + kvp*2];
        dst[0] = r0[e];
        dst[1] = r1[e];
      }
    }
    __syncthreads();

    // QK^T: wave computes 16 rows x 64 cols
    f32x4 sc[4];
    #pragma unroll
    for (int fc=0;fc<4;++fc){
      f32x4 s = {0.f,0.f,0.f,0.f};
      int r = fc*16 + li;
      #pragma unroll
      for (int kc=0;kc<4;++kc){
        bf16x8 kf = *reinterpret_cast<const bf16x8*>((const char*)Klds + r*256 + (((4*kc + g) ^ (r & 7))*16));
        s = mfma16(qf[kc], kf, s);
      }
      sc[fc] = s;
    }

    const float scale = 0.08838834764831845f;  // 1/sqrt(128)
    const int rowg = qb + wid*16 + g*4;
    #pragma unroll
    for (int fc=0;fc<4;++fc){
      int col = c0 + fc*16 + li;
      #pragma unroll
      for (int v=0;v<4;++v){
        float s = sc[fc][v] * scale;
        sc[fc][v] = (col > rowg + v) ? -1e30f : s;
      }
    }

    // online softmax (row reduce over 16-lane column groups)
    float al[4], mnew[4];
    #pragma unroll
    for (int v=0;v<4;++v){
      float tm = fmaxf(fmaxf(sc[0][v], sc[1][v]), fmaxf(sc[2][v], sc[3][v]));
      tm = fmaxf(tm, __shfl_xor(tm, 1));
      tm = fmaxf(tm, __shfl_xor(tm, 2));
      tm = fmaxf(tm, __shfl_xor(tm, 4));
      tm = fmaxf(tm, __shfl_xor(tm, 8));
      mnew[v] = fmaxf(mrun[v], tm);
      al[v] = __expf(mrun[v] - mnew[v]);
      mrun[v] = mnew[v];
    }
    float rs[4] = {0.f,0.f,0.f,0.f};
    #pragma unroll
    for (int fc=0;fc<4;++fc){
      #pragma unroll
      for (int v=0;v<4;++v){
        float p = __expf(sc[fc][v] - mnew[v]);
        rs[v] += p;
        Plds[wid][(g*4 + v)*72 + fc*16 + li] = (bf16)p;
      }
    }
    #pragma unroll
    for (int v=0;v<4;++v){
      float r = rs[v];
      r += __shfl_xor(r, 1); r += __shfl_xor(r, 2);
      r += __shfl_xor(r, 4); r += __shfl_xor(r, 8);
      lrun[v] = lrun[v]*al[v] + r;
    }
    #pragma unroll
    for (int fn=0;fn<8;++fn){
      #pragma unroll
      for (int v=0;v<4;++v) acc[fn][v] *= al[v];
    }

    // PV: O[16 x 128] += P[16 x 64] * V[64 x 128]
    bf16x8 pa[2];
    #pragma unroll
    for (int kc=0;kc<2;++kc)
      pa[kc] = *reinterpret_cast<const bf16x8*>(&Plds[wid][li*72 + kc*32 + g*8]);
    #pragma unroll
    for (int fn=0;fn<8;++fn){
      #pragma unroll
      for (int kc=0;kc<2;++kc){
        bf16x8 bv = *reinterpret_cast<const bf16x8*>(&Vt[(fn*16 + li)*72 + kc*32 + g*8]);
        acc[fn] = mfma16(pa[kc], bv, acc[fn]);
      }
    }
    __syncthreads();
  }

  #pragma unroll
  for (int v=0;v<4;++v){
    float inv = 1.f / lrun[v];
    int row = qb + wid*16 + g*4 + v;
    bf16* dst = O + (((size_t)b*S_ + row)*H_ + h)*D_ + li;
    #pragma unroll
    for (int fn=0;fn<8;++fn)
      dst[fn*16] = (bf16)(acc[fn][v] * inv);
  }
}

extern "C" void kernel_launch(void* const* d_in, const int* in_sizes, int n_in,
                              void* d_out, int out_size, void* d_ws, size_t ws_size,
                              hipStream_t stream)
{
  (void)in_sizes; (void)n_in; (void)out_size; (void)ws_size;
  const float* hid   = (const float*)d_in[0];
  const float* smask = (const float*)d_in[1];
  const float* amask = (const float*)d_in[2];  (void)amask;  // exactly causal; applied structurally
  const int*   pos   = (const int*)d_in[4];
  const float* Wq = (const float*)d_in[5];
  const float* Wk = (const float*)d_in[6];
  const float* Wv = (const float*)d_in[7];
  const float* Wo = (const float*)d_in[8];
  float* out = (float*)d_out;
  char* ws = (char*)d_ws;

  const size_t SZ_TAB = (size_t)S_*64*4;        // 512 KB per table
  const size_t SZ_BSH = (size_t)B_*S_*HID_*2;   // 16 MB bf16 [B,S,HID]
  // buffer reuse plan:
  //  buf1: hidden_bf  -> later v
  //  buf2: hiddenT_bf -> later k
  //  buf3: A_bf       -> later q
  //  buf4: hm_bf      -> later attention output O
  float* cosT = (float*)(ws);
  float* sinT = (float*)(ws + SZ_TAB);
  bf16* buf1 = (bf16*)(ws + 2*SZ_TAB);
  bf16* buf2 = (bf16*)(ws + 2*SZ_TAB + 1*SZ_BSH);
  bf16* buf3 = (bf16*)(ws + 2*SZ_TAB + 2*SZ_BSH);
  bf16* buf4 = (bf16*)(ws + 2*SZ_TAB + 3*SZ_BSH);
  bf16* Wqb = (bf16*)(ws + 2*SZ_TAB + 4*SZ_BSH);
  bf16* Wkb = Wqb + (size_t)HID_*HID_;
  bf16* Wvb = Wkb + (size_t)HID_*HID_;
  bf16* Wob = Wvb + (size_t)HID_*HID_;

  k_tables<<<512,256,0,stream>>>(cosT, sinT);
  k_cvt<<<8192,256,0,stream>>>(hid,   buf1, 2097152);    // hidden -> bf16
  k_cvt<<<8192,256,0,stream>>>(smask ? (const float*)d_in[2] : nullptr, buf3, 2097152); // sum_attn_mask -> bf16
  k_cvt<<<4096,256,0,stream>>>(Wq, Wqb, 1048576);
  k_cvt<<<4096,256,0,stream>>>(Wk, Wkb, 1048576);
  k_cvt<<<4096,256,0,stream>>>(Wv, Wvb, 1048576);
  k_cvt<<<4096,256,0,stream>>>(Wo, Wob, 1048576);
  k_transpose_cvt<<<dim3(32,32,2),256,0,stream>>>(hid, buf2);

  const size_t sBat = (size_t)S_*HID_;  // 4,194,304 elems (== S*S)
  // G1: hm = sum_attn_mask @ hidden + (1-m)*hidden   (batched)
  k_gemm_nt<1><<<dim3(16,16,2),256,0,stream>>>(buf3, buf2, buf4, 2048, sBat, sBat, sBat, 2048, smask, hid);
  // G2: q = hidden_bf @ Wq^T   (M = B*S = 4096)
  k_gemm_nt<0><<<dim3(16,32,1),256,0,stream>>>(buf1, Wqb, buf3, 2048, 0,0,0, 2048, nullptr, nullptr);
  k_rope<<<4096,256,0,stream>>>(buf3, cosT, sinT, pos);
  // G3: k = hm @ Wk^T
  k_gemm_nt<0><<<dim3(16,32,1),256,0,stream>>>(buf4, Wkb, buf2, 2048, 0,0,0, 2048, nullptr, nullptr);
  k_rope<<<4096,256,0,stream>>>(buf2, cosT, sinT, nullptr);
  // G4: v = hm @ Wv^T
  k_gemm_nt<0><<<dim3(16,32,1),256,0,stream>>>(buf4, Wvb, buf1, 2048, 0,0,0, 2048, nullptr, nullptr);
  // attention: O -> buf4 (hm dead)
  k_flash<<<dim3(32,32),256,0,stream>>>(buf3, buf2, buf1, buf4);
  // G5: out = O @ Wo^T -> fp32
  k_gemm_nt<2><<<dim3(16,32,1),256,0,stream>>>(buf4, Wob, out, 2048, 0,0,0, 2048, nullptr, nullptr);
}

// Round 2
// 539.801 us; speedup vs baseline: 1.0939x; 1.0939x over previous
//
#include <hip/hip_runtime.h>
#include <cstdint>
#include <cstddef>

#define B_   2
#define S_   2048
#define H_   16
#define D_   128
#define HID_ 2048

typedef __bf16 bf16;
typedef unsigned short u16;
typedef bf16 bf16x4 __attribute__((ext_vector_type(4)));
typedef bf16 bf16x8 __attribute__((ext_vector_type(8)));
typedef u16  u16x8  __attribute__((ext_vector_type(8)));
typedef float f32x4 __attribute__((ext_vector_type(4)));

__device__ __forceinline__ f32x4 mfma16(bf16x8 a, bf16x8 b, f32x4 c){
  return __builtin_amdgcn_mfma_f32_16x16x32_bf16(a, b, c, 0, 0, 0);
}

__device__ __forceinline__ void gload_lds16(const void* g, void* l){
  __builtin_amdgcn_global_load_lds((const __attribute__((address_space(1))) void*)g,
                                   (__attribute__((address_space(3))) void*)l, 16, 0, 0);
}

// ---------------- RoPE tables: cos/sin [S][64] fp32 ----------------
__global__ void k_tables(float* __restrict__ cosT, float* __restrict__ sinT){
  int id = blockIdx.x*256 + threadIdx.x;      // S*64 = 131072 exact
  int p = id >> 6, i = id & 63;
  double f = (double)p * pow(10000.0, -(double)i/64.0);
  cosT[id] = (float)cos(f);
  sinT[id] = (float)sin(f);
}

// ---------------- fused fp32 -> bf16 converts (6 segments in one dispatch) ----------------
__global__ void k_cvt_all(const float* __restrict__ a0, bf16* __restrict__ o0,
                          const float* __restrict__ a1, bf16* __restrict__ o1,
                          const float* __restrict__ w0, bf16* __restrict__ q0,
                          const float* __restrict__ w1, bf16* __restrict__ q1,
                          const float* __restrict__ w2, bf16* __restrict__ q2,
                          const float* __restrict__ w3, bf16* __restrict__ q3){
  const float* src; bf16* dst; int n4;
  switch (blockIdx.y){
    case 0: src = a0; dst = o0; n4 = 2097152; break;
    case 1: src = a1; dst = o1; n4 = 2097152; break;
    case 2: src = w0; dst = q0; n4 = 1048576; break;
    case 3: src = w1; dst = q1; n4 = 1048576; break;
    case 4: src = w2; dst = q2; n4 = 1048576; break;
    default: src = w3; dst = q3; n4 = 1048576; break;
  }
  int i = blockIdx.x*256 + threadIdx.x;
  if (i >= n4) return;
  f32x4 v = *reinterpret_cast<const f32x4*>(src + (size_t)i*4);
  bf16x4 o;
  o[0]=(bf16)v[0]; o[1]=(bf16)v[1]; o[2]=(bf16)v[2]; o[3]=(bf16)v[3];
  *reinterpret_cast<bf16x4*>(dst + (size_t)i*4) = o;
}

// ---------------- hidden [B][S][HID] f32 -> hiddenT [B][HID][S] bf16 ----------------
__global__ __launch_bounds__(256) void k_transpose_cvt(const float* __restrict__ in, bf16* __restrict__ out){
  __shared__ bf16 t[64][72];
  const int tid = threadIdx.x;
  const int b = blockIdx.z, j0 = blockIdx.x*64, s0 = blockIdx.y*64;
  #pragma unroll
  for (int u0 = 0; u0 < 4; ++u0){
    int u = u0*256 + tid;
    int r = u >> 4, c4 = (u & 15)*4;
    f32x4 v = *reinterpret_cast<const f32x4*>(in + ((size_t)b*S_ + s0 + r)*HID_ + j0 + c4);
    bf16x4 o; o[0]=(bf16)v[0]; o[1]=(bf16)v[1]; o[2]=(bf16)v[2]; o[3]=(bf16)v[3];
    *reinterpret_cast<bf16x4*>(&t[r][c4]) = o;
  }
  __syncthreads();
  #pragma unroll
  for (int u0 = 0; u0 < 4; ++u0){
    int u = u0*256 + tid;
    int r = u >> 4, c4 = (u & 15)*4;    // r: j-local, c4: s-local
    bf16x4 o;
    o[0] = t[c4+0][r]; o[1] = t[c4+1][r]; o[2] = t[c4+2][r]; o[3] = t[c4+3][r];
    *reinterpret_cast<bf16x4*>(out + ((size_t)b*HID_ + j0 + r)*S_ + s0 + c4) = o;
  }
}

// ---------------- NT GEMM: C[M,N] = A[M,K] * B[N,K]^T, bf16 in, fp32 acc ----------------
// EPI 0: store bf16.  EPI 1: += (1-mask[row])*hid[row,col], store bf16 (batched, M=S_).  EPI 2: store fp32.
template<int EPI>
__global__ __launch_bounds__(256) void k_gemm_nt(
    const bf16* __restrict__ A, const bf16* __restrict__ Bm, void* __restrict__ Cv,
    int Kd, size_t sAz, size_t sBz, size_t sCz, int N,
    const float* __restrict__ mask, const float* __restrict__ hid)
{
  const int tid = threadIdx.x;
  const int wid = tid >> 6, lane = tid & 63;
  const int g = lane >> 4, li = lane & 15;
  const int z = blockIdx.z;
  const int m0 = blockIdx.y*128, n0 = blockIdx.x*128;
  const int wm = wid >> 1, wn = wid & 1;
  const bf16* Ab = A + (size_t)z*sAz;
  const bf16* Bb = Bm + (size_t)z*sBz;

  __shared__ bf16 lA[128*64];
  __shared__ bf16 lB[128*64];

  f32x4 acc[4][4];
  #pragma unroll
  for (int i=0;i<4;++i)
    #pragma unroll
    for (int j=0;j<4;++j)
      acc[i][j] = {0.f,0.f,0.f,0.f};

  for (int k0 = 0; k0 < Kd; k0 += 64){
    #pragma unroll
    for (int j=0;j<4;++j){
      int ci = j*256 + tid;
      int r = ci >> 3, cb = ci & 7;     // 8 chunks of 16B per 64-elem row
      gload_lds16(Ab + (size_t)(m0 + r)*Kd + k0 + cb*8, (char*)lA + (j*256 + wid*64)*16);
      gload_lds16(Bb + (size_t)(n0 + r)*Kd + k0 + cb*8, (char*)lB + (j*256 + wid*64)*16);
    }
    __syncthreads();
    #pragma unroll
    for (int kk=0;kk<2;++kk){
      bf16x8 af[4], bfm[4];
      #pragma unroll
      for (int i=0;i<4;++i){
        af[i]  = *reinterpret_cast<const bf16x8*>(&lA[(wm*64 + i*16 + li)*64 + kk*32 + g*8]);
        bfm[i] = *reinterpret_cast<const bf16x8*>(&lB[(wn*64 + i*16 + li)*64 + kk*32 + g*8]);
      }
      #pragma unroll
      for (int i=0;i<4;++i)
        #pragma unroll
        for (int j=0;j<4;++j)
          acc[i][j] = mfma16(af[i], bfm[j], acc[i][j]);
    }
    __syncthreads();
  }

  #pragma unroll
  for (int i=0;i<4;++i){
    #pragma unroll
    for (int j=0;j<4;++j){
      #pragma unroll
      for (int v=0;v<4;++v){
        int row = m0 + wm*64 + i*16 + g*4 + v;   // C/D: col=lane&15, row=(lane>>4)*4+reg
        int col = n0 + wn*64 + j*16 + li;
        float x = acc[i][j][v];
        if (EPI == 1){
          x += (1.f - mask[z*S_ + row]) * hid[((size_t)z*S_ + row)*HID_ + col];
          ((bf16*)Cv)[(size_t)z*sCz + (size_t)row*N + col] = (bf16)x;
        } else if (EPI == 0){
          ((bf16*)Cv)[(size_t)row*N + col] = (bf16)x;
        } else {
          ((float*)Cv)[(size_t)row*N + col] = x;
        }
      }
    }
  }
}

// ---------------- RoPE in place on [B,S,H,D] bf16 ----------------
__global__ void k_rope(bf16* __restrict__ X, const float* __restrict__ cosT,
                       const float* __restrict__ sinT, const int* __restrict__ pos){
  int id = blockIdx.x*256 + threadIdx.x;   // B*S*H*16 = 1048576 exact
  int d4 = (id & 15)*4;
  int h  = (id >> 4) & 15;
  int s  = (id >> 8) & 2047;
  int b  = id >> 19;
  int p = pos ? pos[b*S_ + s] : s;
  size_t base = (((size_t)b*S_ + s)*H_ + h)*D_ + d4;
  f32x4 c  = *reinterpret_cast<const f32x4*>(cosT + (size_t)p*64 + d4);
  f32x4 sn = *reinterpret_cast<const f32x4*>(sinT + (size_t)p*64 + d4);
  bf16x4 x1 = *reinterpret_cast<bf16x4*>(X + base);
  bf16x4 x2 = *reinterpret_cast<bf16x4*>(X + base + 64);
  bf16x4 o1, o2;
  #pragma unroll
  for (int i=0;i<4;++i){
    float a = (float)x1[i], bb = (float)x2[i];
    o1[i] = (bf16)(a*c[i] - bb*sn[i]);
    o2[i] = (bf16)(bb*c[i] + a*sn[i]);
  }
  *reinterpret_cast<bf16x4*>(X + base) = o1;
  *reinterpret_cast<bf16x4*>(X + base + 64) = o2;
}

// ---------------- causal flash attention ----------------
// Q,K,V,O: [B,S,H,D] bf16. 1-D grid of 512 blocks (heavy/light paired), 256 thr
// (4 waves, 32 q-rows/wave = 128 q-rows/block). KV tile = 64.
__global__ __launch_bounds__(256) void k_flash(const bf16* __restrict__ Q, const bf16* __restrict__ K,
                                               const bf16* __restrict__ V, bf16* __restrict__ O)
{
  const int tid = threadIdx.x;
  const int wid = tid >> 6, lane = tid & 63;
  const int g = lane >> 4, li = lane & 15;
  // heavy/light pairing: consecutive block ids sum to a constant tile count
  const int id = blockIdx.x;
  const int lin = ((id & 1) == 0) ? (id >> 1) : (511 - (id >> 1));
  const int qx = lin & 15;            // q-tile index (nt = 2*qx+2)
  const int bh = lin >> 4;
  const int b = bh >> 4, h = bh & 15;
  const int qb = qx * 128;

  __shared__ bf16 Klds[64*128];       // linear dest, source chunk-XOR swizzled
  __shared__ char VtB[128*128];       // V^T [d][kv] bf16, XOR-swizzled 16B chunks
  __shared__ bf16 Plds[4][32*72];     // per-wave P (32 rows x 64 cols, pad 72)

  // Q fragments: 2 row-blocks of 16
  bf16x8 qf[2][4];
  #pragma unroll
  for (int rb=0;rb<2;++rb){
    const bf16* Qp = Q + (((size_t)b*S_ + qb + wid*32 + rb*16 + li)*H_ + h)*D_;
    #pragma unroll
    for (int kc=0;kc<4;++kc)
      qf[rb][kc] = *reinterpret_cast<const bf16x8*>(Qp + kc*32 + g*8);
  }

  float mrun[2][4], lrun[2][4];
  f32x4 acc[2][8];
  #pragma unroll
  for (int rb=0;rb<2;++rb){
    #pragma unroll
    for (int v=0;v<4;++v){ mrun[rb][v] = -1e30f; lrun[rb][v] = 0.f; }
    #pragma unroll
    for (int fn=0;fn<8;++fn) acc[rb][fn] = {0.f,0.f,0.f,0.f};
  }

  const int nt = 2*qx + 2;
  for (int t=0; t<nt; ++t){
    const int c0 = t*64;
    // ---- stage K tile [64 kv][128 d], 16B chunks, source XOR-swizzled ----
    #pragma unroll
    for (int j=0;j<4;++j){
      int ci = j*256 + tid;
      int r = ci >> 4, cb = ci & 15;
      const char* src = (const char*)(K + (((size_t)b*S_ + c0 + r)*H_ + h)*D_) + ((cb ^ (r & 7)) * 16);
      gload_lds16(src, (char*)Klds + (j*256 + wid*64)*16);
    }
    // ---- stage V transposed [d][kv], XOR-swizzled chunks, packed u32 writes ----
    #pragma unroll
    for (int j=0;j<2;++j){
      int u = j*256 + tid;
      int dc = u & 15, kvp = u >> 4;        // dc: d-chunk of 8; kvp: kv pair
      const u16* vsrc = (const u16*)(V + (((size_t)b*S_ + c0 + kvp*2)*H_ + h)*D_) + dc*8;
      u16x8 r0 = *reinterpret_cast<const u16x8*>(vsrc);
      u16x8 r1 = *reinterpret_cast<const u16x8*>(vsrc + H_*D_);
      #pragma unroll
      for (int e=0;e<8;++e){
        int r = dc*8 + e;
        int swz = (r ^ (r >> 3)) & 7;
        int addr = r*128 + (((kvp >> 2) ^ swz) << 4) + ((kvp << 2) & 12);
        *reinterpret_cast<uint32_t*>(VtB + addr) = (uint32_t)r0[e] | ((uint32_t)r1[e] << 16);
      }
    }
    __syncthreads();

    // ---- QK^T: wave computes 32 rows x 64 cols ----
    f32x4 sc[2][4];
    #pragma unroll
    for (int fc=0;fc<4;++fc){
      int r = fc*16 + li;
      bf16x8 kf[4];
      #pragma unroll
      for (int kc=0;kc<4;++kc)
        kf[kc] = *reinterpret_cast<const bf16x8*>((const char*)Klds + r*256 + (((4*kc + g) ^ (r & 7))*16));
      __builtin_amdgcn_s_setprio(1);
      #pragma unroll
      for (int rb=0;rb<2;++rb){
        f32x4 s = {0.f,0.f,0.f,0.f};
        #pragma unroll
        for (int kc=0;kc<4;++kc)
          s = mfma16(qf[rb][kc], kf[kc], s);
        sc[rb][fc] = s;
      }
      __builtin_amdgcn_s_setprio(0);
    }

    // ---- mask + online softmax (per row-block) ----
    const float scale = 0.08838834764831845f;  // 1/sqrt(128)
    #pragma unroll
    for (int rb=0;rb<2;++rb){
      const int rowg = qb + wid*32 + rb*16 + g*4;
      #pragma unroll
      for (int fc=0;fc<4;++fc){
        int col = c0 + fc*16 + li;
        #pragma unroll
        for (int v=0;v<4;++v){
          float s = sc[rb][fc][v] * scale;
          sc[rb][fc][v] = (col > rowg + v) ? -1e30f : s;
        }
      }
      float mnew[4], al[4];
      #pragma unroll
      for (int v=0;v<4;++v){
        float tm = fmaxf(fmaxf(sc[rb][0][v], sc[rb][1][v]), fmaxf(sc[rb][2][v], sc[rb][3][v]));
        tm = fmaxf(tm, __shfl_xor(tm, 1));
        tm = fmaxf(tm, __shfl_xor(tm, 2));
        tm = fmaxf(tm, __shfl_xor(tm, 4));
        tm = fmaxf(tm, __shfl_xor(tm, 8));
        mnew[v] = fmaxf(mrun[rb][v], tm);
        al[v] = __expf(mrun[rb][v] - mnew[v]);
        mrun[rb][v] = mnew[v];
      }
      float rs[4] = {0.f,0.f,0.f,0.f};
      #pragma unroll
      for (int fc=0;fc<4;++fc){
        #pragma unroll
        for (int v=0;v<4;++v){
          float p = __expf(sc[rb][fc][v] - mnew[v]);
          rs[v] += p;
          Plds[wid][(rb*16 + g*4 + v)*72 + fc*16 + li] = (bf16)p;
        }
      }
      #pragma unroll
      for (int v=0;v<4;++v){
        float r = rs[v];
        r += __shfl_xor(r, 1); r += __shfl_xor(r, 2);
        r += __shfl_xor(r, 4); r += __shfl_xor(r, 8);
        lrun[rb][v] = lrun[rb][v]*al[v] + r;
      }
      #pragma unroll
      for (int fn=0;fn<8;++fn){
        #pragma unroll
        for (int v=0;v<4;++v) acc[rb][fn][v] *= al[v];
      }
    }

    // ---- PV: O[32 x 128] += P[32 x 64] * V[64 x 128] ----
    bf16x8 pa[2][2];
    #pragma unroll
    for (int rb=0;rb<2;++rb)
      #pragma unroll
      for (int kc=0;kc<2;++kc)
        pa[rb][kc] = *reinterpret_cast<const bf16x8*>(&Plds[wid][(rb*16 + li)*72 + kc*32 + g*8]);
    #pragma unroll
    for (int fn=0;fn<8;++fn){
      int r = fn*16 + li;
      int swz = (r ^ (r >> 3)) & 7;
      bf16x8 bv[2];
      #pragma unroll
      for (int kc=0;kc<2;++kc)
        bv[kc] = *reinterpret_cast<const bf16x8*>(VtB + r*128 + (((kc*4 + g) ^ swz) << 4));
      __builtin_amdgcn_s_setprio(1);
      #pragma unroll
      for (int rb=0;rb<2;++rb)
        #pragma unroll
        for (int kc=0;kc<2;++kc)
          acc[rb][fn] = mfma16(pa[rb][kc], bv[kc], acc[rb][fn]);
      __builtin_amdgcn_s_setprio(0);
    }
    __syncthreads();
  }

  #pragma unroll
  for (int rb=0;rb<2;++rb){
    #pragma unroll
    for (int v=0;v<4;++v){
      float inv = 1.f / lrun[rb][v];
      int row = qb + wid*32 + rb*16 + g*4 + v;
      bf16* dst = O + (((size_t)b*S_ + row)*H_ + h)*D_ + li;
      #pragma unroll
      for (int fn=0;fn<8;++fn)
        dst[fn*16] = (bf16)(acc[rb][fn][v] * inv);
    }
  }
}

extern "C" void kernel_launch(void* const* d_in, const int* in_sizes, int n_in,
                              void* d_out, int out_size, void* d_ws, size_t ws_size,
                              hipStream_t stream)
{
  (void)in_sizes; (void)n_in; (void)out_size; (void)ws_size;
  const float* hid   = (const float*)d_in[0];
  const float* smask = (const float*)d_in[1];
  const float* samat = (const float*)d_in[2];
  const int*   pos   = (const int*)d_in[4];
  const float* Wq = (const float*)d_in[5];
  const float* Wk = (const float*)d_in[6];
  const float* Wv = (const float*)d_in[7];
  const float* Wo = (const float*)d_in[8];
  float* out = (float*)d_out;
  char* ws = (char*)d_ws;

  const size_t SZ_TAB = (size_t)S_*64*4;        // 512 KB per table
  const size_t SZ_BSH = (size_t)B_*S_*HID_*2;   // 16 MB bf16 [B,S,HID]
  // buffer reuse plan:
  //  buf1: hidden_bf  -> later v
  //  buf2: hiddenT_bf -> later k
  //  buf3: A_bf       -> later q
  //  buf4: hm_bf      -> later attention output O
  float* cosT = (float*)(ws);
  float* sinT = (float*)(ws + SZ_TAB);
  bf16* buf1 = (bf16*)(ws + 2*SZ_TAB);
  bf16* buf2 = (bf16*)(ws + 2*SZ_TAB + 1*SZ_BSH);
  bf16* buf3 = (bf16*)(ws + 2*SZ_TAB + 2*SZ_BSH);
  bf16* buf4 = (bf16*)(ws + 2*SZ_TAB + 3*SZ_BSH);
  bf16* Wqb = (bf16*)(ws + 2*SZ_TAB + 4*SZ_BSH);
  bf16* Wkb = Wqb + (size_t)HID_*HID_;
  bf16* Wvb = Wkb + (size_t)HID_*HID_;
  bf16* Wob = Wvb + (size_t)HID_*HID_;

  k_tables<<<512,256,0,stream>>>(cosT, sinT);
  k_cvt_all<<<dim3(8192,6),256,0,stream>>>(hid, buf1, samat, buf3,
                                           Wq, Wqb, Wk, Wkb, Wv, Wvb, Wo, Wob);
  k_transpose_cvt<<<dim3(32,32,2),256,0,stream>>>(hid, buf2);

  const size_t sBat = (size_t)S_*HID_;  // 4,194,304 elems (== S*S)
  // G1: hm = sum_attn_mask @ hidden + (1-m)*hidden   (batched)
  k_gemm_nt<1><<<dim3(16,16,2),256,0,stream>>>(buf3, buf2, buf4, 2048, sBat, sBat, sBat, 2048, smask, hid);
  // G2: q = hidden_bf @ Wq^T   (M = B*S = 4096)
  k_gemm_nt<0><<<dim3(16,32,1),256,0,stream>>>(buf1, Wqb, buf3, 2048, 0,0,0, 2048, nullptr, nullptr);
  k_rope<<<4096,256,0,stream>>>(buf3, cosT, sinT, pos);
  // G3: k = hm @ Wk^T
  k_gemm_nt<0><<<dim3(16,32,1),256,0,stream>>>(buf4, Wkb, buf2, 2048, 0,0,0, 2048, nullptr, nullptr);
  k_rope<<<4096,256,0,stream>>>(buf2, cosT, sinT, nullptr);
  // G4: v = hm @ Wv^T
  k_gemm_nt<0><<<dim3(16,32,1),256,0,stream>>>(buf4, Wvb, buf1, 2048, 0,0,0, 2048, nullptr, nullptr);
  // attention: O -> buf4 (hm dead)
  k_flash<<<dim3(512),256,0,stream>>>(buf3, buf2, buf1, buf4);
  // G5: out = O @ Wo^T -> fp32
  k_gemm_nt<2><<<dim3(16,32,1),256,0,stream>>>(buf4, Wob, out, 2048, 0,0,0, 2048, nullptr, nullptr);
}

// Round 3
// 429.500 us; speedup vs baseline: 1.3748x; 1.2568x over previous
//
#include <hip/hip_runtime.h>
#include <cstdint>
#include <cstddef>

#define B_   2
#define S_   2048
#define H_   16
#define D_   128
#define HID_ 2048

typedef __bf16 bf16;
typedef unsigned short u16;
typedef bf16 bf16x4 __attribute__((ext_vector_type(4)));
typedef bf16 bf16x8 __attribute__((ext_vector_type(8)));
typedef u16  u16x8  __attribute__((ext_vector_type(8)));
typedef float f32x4 __attribute__((ext_vector_type(4)));

__device__ unsigned g_work;   // work-stealing counter; zeroed by k_tables each launch

__device__ __forceinline__ f32x4 mfma16(bf16x8 a, bf16x8 b, f32x4 c){
  return __builtin_amdgcn_mfma_f32_16x16x32_bf16(a, b, c, 0, 0, 0);
}

__device__ __forceinline__ void gload_lds16(const void* g, void* l){
  __builtin_amdgcn_global_load_lds((const __attribute__((address_space(1))) void*)g,
                                   (__attribute__((address_space(3))) void*)l, 16, 0, 0);
}

// ---------------- RoPE tables: cos/sin [S][64] fp32 (+ work counter reset) ----------------
__global__ void k_tables(float* __restrict__ cosT, float* __restrict__ sinT){
  if (blockIdx.x == 0 && threadIdx.x == 0) g_work = 0u;
  int id = blockIdx.x*256 + threadIdx.x;      // S*64 = 131072 exact
  int p = id >> 6, i = id & 63;
  double f = (double)p * pow(10000.0, -(double)i/64.0);
  cosT[id] = (float)cos(f);
  sinT[id] = (float)sin(f);
}

// ---------------- fused fp32 -> bf16 converts (6 segments in one dispatch) ----------------
__global__ void k_cvt_all(const float* __restrict__ a0, bf16* __restrict__ o0,
                          const float* __restrict__ a1, bf16* __restrict__ o1,
                          const float* __restrict__ w0, bf16* __restrict__ q0,
                          const float* __restrict__ w1, bf16* __restrict__ q1,
                          const float* __restrict__ w2, bf16* __restrict__ q2,
                          const float* __restrict__ w3, bf16* __restrict__ q3){
  const float* src; bf16* dst; int n4;
  switch (blockIdx.y){
    case 0: src = a0; dst = o0; n4 = 2097152; break;
    case 1: src = a1; dst = o1; n4 = 2097152; break;
    case 2: src = w0; dst = q0; n4 = 1048576; break;
    case 3: src = w1; dst = q1; n4 = 1048576; break;
    case 4: src = w2; dst = q2; n4 = 1048576; break;
    default: src = w3; dst = q3; n4 = 1048576; break;
  }
  int i = blockIdx.x*256 + threadIdx.x;
  if (i >= n4) return;
  f32x4 v = *reinterpret_cast<const f32x4*>(src + (size_t)i*4);
  bf16x4 o;
  o[0]=(bf16)v[0]; o[1]=(bf16)v[1]; o[2]=(bf16)v[2]; o[3]=(bf16)v[3];
  *reinterpret_cast<bf16x4*>(dst + (size_t)i*4) = o;
}

// ---------------- hidden [B][S][HID] f32 -> hiddenT [B][HID][S] bf16 ----------------
__global__ __launch_bounds__(256) void k_transpose_cvt(const float* __restrict__ in, bf16* __restrict__ out){
  __shared__ bf16 t[64][72];
  const int tid = threadIdx.x;
  const int b = blockIdx.z, j0 = blockIdx.x*64, s0 = blockIdx.y*64;
  #pragma unroll
  for (int u0 = 0; u0 < 4; ++u0){
    int u = u0*256 + tid;
    int r = u >> 4, c4 = (u & 15)*4;
    f32x4 v = *reinterpret_cast<const f32x4*>(in + ((size_t)b*S_ + s0 + r)*HID_ + j0 + c4);
    bf16x4 o; o[0]=(bf16)v[0]; o[1]=(bf16)v[1]; o[2]=(bf16)v[2]; o[3]=(bf16)v[3];
    *reinterpret_cast<bf16x4*>(&t[r][c4]) = o;
  }
  __syncthreads();
  #pragma unroll
  for (int u0 = 0; u0 < 4; ++u0){
    int u = u0*256 + tid;
    int r = u >> 4, c4 = (u & 15)*4;    // r: j-local, c4: s-local
    bf16x4 o;
    o[0] = t[c4+0][r]; o[1] = t[c4+1][r]; o[2] = t[c4+2][r]; o[3] = t[c4+3][r];
    *reinterpret_cast<bf16x4*>(out + ((size_t)b*HID_ + j0 + r)*S_ + s0 + c4) = o;
  }
}

// ---------------- NT GEMM: C[M,N] = A[M,K] * B[N,K]^T, bf16 in, fp32 acc ----------------
// EPI 0: store bf16.  EPI 1: += (1-mask[row])*hid[row,col], store bf16 (batched, M=S_).  EPI 2: store fp32.
template<int EPI>
__global__ __launch_bounds__(256) void k_gemm_nt(
    const bf16* __restrict__ A, const bf16* __restrict__ Bm, void* __restrict__ Cv,
    int Kd, size_t sAz, size_t sBz, size_t sCz, int N,
    const float* __restrict__ mask, const float* __restrict__ hid)
{
  const int tid = threadIdx.x;
  const int wid = tid >> 6, lane = tid & 63;
  const int g = lane >> 4, li = lane & 15;
  const int z = blockIdx.z;
  const int m0 = blockIdx.y*128, n0 = blockIdx.x*128;
  const int wm = wid >> 1, wn = wid & 1;
  const bf16* Ab = A + (size_t)z*sAz;
  const bf16* Bb = Bm + (size_t)z*sBz;

  __shared__ bf16 lA[128*64];
  __shared__ bf16 lB[128*64];

  f32x4 acc[4][4];
  #pragma unroll
  for (int i=0;i<4;++i)
    #pragma unroll
    for (int j=0;j<4;++j)
      acc[i][j] = {0.f,0.f,0.f,0.f};

  for (int k0 = 0; k0 < Kd; k0 += 64){
    #pragma unroll
    for (int j=0;j<4;++j){
      int ci = j*256 + tid;
      int r = ci >> 3, cb = ci & 7;     // 8 chunks of 16B per 64-elem row
      gload_lds16(Ab + (size_t)(m0 + r)*Kd + k0 + cb*8, (char*)lA + (j*256 + wid*64)*16);
      gload_lds16(Bb + (size_t)(n0 + r)*Kd + k0 + cb*8, (char*)lB + (j*256 + wid*64)*16);
    }
    __syncthreads();
    #pragma unroll
    for (int kk=0;kk<2;++kk){
      bf16x8 af[4], bfm[4];
      #pragma unroll
      for (int i=0;i<4;++i){
        af[i]  = *reinterpret_cast<const bf16x8*>(&lA[(wm*64 + i*16 + li)*64 + kk*32 + g*8]);
        bfm[i] = *reinterpret_cast<const bf16x8*>(&lB[(wn*64 + i*16 + li)*64 + kk*32 + g*8]);
      }
      #pragma unroll
      for (int i=0;i<4;++i)
        #pragma unroll
        for (int j=0;j<4;++j)
          acc[i][j] = mfma16(af[i], bfm[j], acc[i][j]);
    }
    __syncthreads();
  }

  #pragma unroll
  for (int i=0;i<4;++i){
    #pragma unroll
    for (int j=0;j<4;++j){
      #pragma unroll
      for (int v=0;v<4;++v){
        int row = m0 + wm*64 + i*16 + g*4 + v;   // C/D: col=lane&15, row=(lane>>4)*4+reg
        int col = n0 + wn*64 + j*16 + li;
        float x = acc[i][j][v];
        if (EPI == 1){
          x += (1.f - mask[z*S_ + row]) * hid[((size_t)z*S_ + row)*HID_ + col];
          ((bf16*)Cv)[(size_t)z*sCz + (size_t)row*N + col] = (bf16)x;
        } else if (EPI == 0){
          ((bf16*)Cv)[(size_t)row*N + col] = (bf16)x;
        } else {
          ((float*)Cv)[(size_t)row*N + col] = x;
        }
      }
    }
  }
}

// ---------------- RoPE in place on [B,S,H,D] bf16 ----------------
__global__ void k_rope(bf16* __restrict__ X, const float* __restrict__ cosT,
                       const float* __restrict__ sinT, const int* __restrict__ pos){
  int id = blockIdx.x*256 + threadIdx.x;   // B*S*H*16 = 1048576 exact
  int d4 = (id & 15)*4;
  int h  = (id >> 4) & 15;
  int s  = (id >> 8) & 2047;
  int b  = id >> 19;
  int p = pos ? pos[b*S_ + s] : s;
  size_t base = (((size_t)b*S_ + s)*H_ + h)*D_ + d4;
  f32x4 c  = *reinterpret_cast<const f32x4*>(cosT + (size_t)p*64 + d4);
  f32x4 sn = *reinterpret_cast<const f32x4*>(sinT + (size_t)p*64 + d4);
  bf16x4 x1 = *reinterpret_cast<bf16x4*>(X + base);
  bf16x4 x2 = *reinterpret_cast<bf16x4*>(X + base + 64);
  bf16x4 o1, o2;
  #pragma unroll
  for (int i=0;i<4;++i){
    float a = (float)x1[i], bb = (float)x2[i];
    o1[i] = (bf16)(a*c[i] - bb*sn[i]);
    o2[i] = (bf16)(bb*c[i] + a*sn[i]);
  }
  *reinterpret_cast<bf16x4*>(X + base) = o1;
  *reinterpret_cast<bf16x4*>(X + base + 64) = o2;
}

// ---------------- causal flash attention, persistent work-stealing ----------------
// Q,K,V,O: [B,S,H,D] bf16. 768 persistent blocks (3/CU), 256 thr (4 waves,
// 16 q-rows/wave = 64 q-rows/item). Items = 1024 (bh x qtile), heavy-first.
__global__ __launch_bounds__(256,3) void k_flash(const bf16* __restrict__ Q, const bf16* __restrict__ K,
                                                 const bf16* __restrict__ V, bf16* __restrict__ O)
{
  const int tid = threadIdx.x;
  const int wid = tid >> 6, lane = tid & 63;
  const int g = lane >> 4, li = lane & 15;

  __shared__ bf16 Klds[64*128];       // linear dest, source chunk-XOR swizzled
  __shared__ char VtB[128*128];       // V^T [d][kv] bf16, XOR-swizzled 16B chunks
  __shared__ bf16 Plds[4][16*72];     // per-wave P (16 rows x 64 cols, pad 72)
  __shared__ int s_item;

  // V-staging thread roles (fixed): two units per thread
  const int dc0 = tid & 15,          kvp0 = tid >> 4;          // unit j=0
  const int dc1 = (256 + tid) & 15,  kvp1 = (256 + tid) >> 4;  // unit j=1

  for (;;) {
    if (tid == 0) s_item = (int)atomicAdd(&g_work, 1u);
    __syncthreads();
    const int w = s_item;
    if (w >= 1024) return;

    const int qx = 31 - (w >> 5);     // heavy-first
    const int bh = w & 31;
    const int b = bh >> 4, h = bh & 15;
    const int qb = qx * 64;
    const int nt = qx + 1;

    const size_t headoff = ((size_t)b*S_*H_ + h)*D_;
    const bf16* Kh = K + headoff;
    const u16*  Vh = (const u16*)(V + headoff);

    // Q fragments: 16 rows/wave
    const bf16* Qp = Q + headoff + (size_t)(qb + wid*16 + li)*H_*D_;
    bf16x8 qf[4];
    #pragma unroll
    for (int kc=0;kc<4;++kc)
      qf[kc] = *reinterpret_cast<const bf16x8*>(Qp + kc*32 + g*8);

    float mrun[4], lrun[4];
    f32x4 acc[8];
    #pragma unroll
    for (int v=0;v<4;++v){ mrun[v] = -1e30f; lrun[v] = 0.f; }
    #pragma unroll
    for (int fn=0;fn<8;++fn) acc[fn] = {0.f,0.f,0.f,0.f};

    // prefetch V for t=0
    u16x8 vp[4];
    {
      const u16* s0p = Vh + (size_t)(kvp0*2)*H_*D_ + dc0*8;
      const u16* s1p = Vh + (size_t)(kvp1*2)*H_*D_ + dc1*8;
      vp[0] = *reinterpret_cast<const u16x8*>(s0p);
      vp[1] = *reinterpret_cast<const u16x8*>(s0p + H_*D_);
      vp[2] = *reinterpret_cast<const u16x8*>(s1p);
      vp[3] = *reinterpret_cast<const u16x8*>(s1p + H_*D_);
    }

    for (int t=0; t<nt; ++t){
      const int c0 = t*64;
      // ---- stage K tile [64 kv][128 d], 16B chunks, source XOR-swizzled ----
      #pragma unroll
      for (int j=0;j<4;++j){
        int ci = j*256 + tid;
        int r = ci >> 4, cb = ci & 15;
        const char* src = (const char*)(Kh + (size_t)(c0 + r)*H_*D_) + ((cb ^ (r & 7)) * 16);
        gload_lds16(src, (char*)Klds + (j*256 + wid*64)*16);
      }
      // ---- write prefetched V regs -> VtB (transposed, swizzled, u32-packed) ----
      #pragma unroll
      for (int j=0;j<2;++j){
        int dc = j ? dc1 : dc0, kvp = j ? kvp1 : kvp0;
        #pragma unroll
        for (int e=0;e<8;++e){
          int r = dc*8 + e;
          int swz = (r ^ (r >> 3)) & 7;
          int addr = r*128 + (((kvp >> 2) ^ swz) << 4) + ((kvp << 2) & 12);
          *reinterpret_cast<uint32_t*>(VtB + addr) =
              (uint32_t)vp[j*2+0][e] | ((uint32_t)vp[j*2+1][e] << 16);
        }
      }
      __syncthreads();
      // ---- prefetch V for next tile (latency hides under compute) ----
      if (t+1 < nt){
        const u16* s0p = Vh + (size_t)(c0 + 64 + kvp0*2)*H_*D_ + dc0*8;
        const u16* s1p = Vh + (size_t)(c0 + 64 + kvp1*2)*H_*D_ + dc1*8;
        vp[0] = *reinterpret_cast<const u16x8*>(s0p);
        vp[1] = *reinterpret_cast<const u16x8*>(s0p + H_*D_);
        vp[2] = *reinterpret_cast<const u16x8*>(s1p);
        vp[3] = *reinterpret_cast<const u16x8*>(s1p + H_*D_);
      }

      // ---- QK^T: wave computes 16 rows x 64 cols ----
      f32x4 sc[4];
      #pragma unroll
      for (int fc=0;fc<4;++fc){
        int r = fc*16 + li;
        bf16x8 kf[4];
        #pragma unroll
        for (int kc=0;kc<4;++kc)
          kf[kc] = *reinterpret_cast<const bf16x8*>((const char*)Klds + r*256 + (((4*kc + g) ^ (r & 7))*16));
        f32x4 s = {0.f,0.f,0.f,0.f};
        __builtin_amdgcn_s_setprio(1);
        #pragma unroll
        for (int kc=0;kc<4;++kc)
          s = mfma16(qf[kc], kf[kc], s);
        __builtin_amdgcn_s_setprio(0);
        sc[fc] = s;
      }

      // ---- scale (+ causal mask on diagonal tile only) ----
      const float scale = 0.08838834764831845f;  // 1/sqrt(128)
      if (t == nt-1){
        const int rowg = qb + wid*16 + g*4;
        #pragma unroll
        for (int fc=0;fc<4;++fc){
          int col = c0 + fc*16 + li;
          #pragma unroll
          for (int v=0;v<4;++v){
            float s = sc[fc][v] * scale;
            sc[fc][v] = (col > rowg + v) ? -1e30f : s;
          }
        }
      } else {
        #pragma unroll
        for (int fc=0;fc<4;++fc)
          #pragma unroll
          for (int v=0;v<4;++v)
            sc[fc][v] *= scale;
      }

      // ---- online softmax with defer-max (THR=8) ----
      float tm[4];
      #pragma unroll
      for (int v=0;v<4;++v){
        float m2 = fmaxf(fmaxf(sc[0][v], sc[1][v]), fmaxf(sc[2][v], sc[3][v]));
        m2 = fmaxf(m2, __shfl_xor(m2, 1));
        m2 = fmaxf(m2, __shfl_xor(m2, 2));
        m2 = fmaxf(m2, __shfl_xor(m2, 4));
        m2 = fmaxf(m2, __shfl_xor(m2, 8));
        tm[v] = m2;
      }
      bool need = false;
      #pragma unroll
      for (int v=0;v<4;++v) need = need || (tm[v] > mrun[v] + 8.f);
      if (__any(need)){
        float al[4];
        #pragma unroll
        for (int v=0;v<4;++v){
          float mnew = fmaxf(mrun[v], tm[v]);
          al[v] = __expf(mrun[v] - mnew);
          mrun[v] = mnew;
          lrun[v] *= al[v];
        }
        #pragma unroll
        for (int fn=0;fn<8;++fn)
          #pragma unroll
          for (int v=0;v<4;++v) acc[fn][v] *= al[v];
      }
      float rs[4] = {0.f,0.f,0.f,0.f};
      #pragma unroll
      for (int fc=0;fc<4;++fc){
        #pragma unroll
        for (int v=0;v<4;++v){
          float p = __expf(sc[fc][v] - mrun[v]);
          rs[v] += p;
          Plds[wid][(g*4 + v)*72 + fc*16 + li] = (bf16)p;
        }
      }
      #pragma unroll
      for (int v=0;v<4;++v){
        float r = rs[v];
        r += __shfl_xor(r, 1); r += __shfl_xor(r, 2);
        r += __shfl_xor(r, 4); r += __shfl_xor(r, 8);
        lrun[v] += r;
      }

      // ---- PV: O[16 x 128] += P[16 x 64] * V[64 x 128] ----
      bf16x8 pa[2];
      #pragma unroll
      for (int kc=0;kc<2;++kc)
        pa[kc] = *reinterpret_cast<const bf16x8*>(&Plds[wid][li*72 + kc*32 + g*8]);
      #pragma unroll
      for (int fn=0;fn<8;++fn){
        int r = fn*16 + li;
        int swz = (r ^ (r >> 3)) & 7;
        bf16x8 bv[2];
        #pragma unroll
        for (int kc=0;kc<2;++kc)
          bv[kc] = *reinterpret_cast<const bf16x8*>(VtB + r*128 + (((kc*4 + g) ^ swz) << 4));
        __builtin_amdgcn_s_setprio(1);
        #pragma unroll
        for (int kc=0;kc<2;++kc)
          acc[fn] = mfma16(pa[kc], bv[kc], acc[fn]);
        __builtin_amdgcn_s_setprio(0);
      }
      __syncthreads();
    }

    // ---- epilogue: normalize + write O ----
    #pragma unroll
    for (int v=0;v<4;++v){
      float inv = 1.f / lrun[v];
      int row = qb + wid*16 + g*4 + v;
      bf16* dst = O + headoff + (size_t)row*H_*D_ + li;
      #pragma unroll
      for (int fn=0;fn<8;++fn)
        dst[fn*16] = (bf16)(acc[fn][v] * inv);
    }
  }
}

extern "C" void kernel_launch(void* const* d_in, const int* in_sizes, int n_in,
                              void* d_out, int out_size, void* d_ws, size_t ws_size,
                              hipStream_t stream)
{
  (void)in_sizes; (void)n_in; (void)out_size; (void)ws_size;
  const float* hid   = (const float*)d_in[0];
  const float* smask = (const float*)d_in[1];
  const float* samat = (const float*)d_in[2];
  const int*   pos   = (const int*)d_in[4];
  const float* Wq = (const float*)d_in[5];
  const float* Wk = (const float*)d_in[6];
  const float* Wv = (const float*)d_in[7];
  const float* Wo = (const float*)d_in[8];
  float* out = (float*)d_out;
  char* ws = (char*)d_ws;

  const size_t SZ_TAB = (size_t)S_*64*4;        // 512 KB per table
  const size_t SZ_BSH = (size_t)B_*S_*HID_*2;   // 16 MB bf16 [B,S,HID]
  // buffer reuse plan:
  //  buf1: hidden_bf  -> later v
  //  buf2: hiddenT_bf -> later k
  //  buf3: A_bf       -> later q
  //  buf4: hm_bf      -> later attention output O
  float* cosT = (float*)(ws);
  float* sinT = (float*)(ws + SZ_TAB);
  bf16* buf1 = (bf16*)(ws + 2*SZ_TAB);
  bf16* buf2 = (bf16*)(ws + 2*SZ_TAB + 1*SZ_BSH);
  bf16* buf3 = (bf16*)(ws + 2*SZ_TAB + 2*SZ_BSH);
  bf16* buf4 = (bf16*)(ws + 2*SZ_TAB + 3*SZ_BSH);
  bf16* Wqb = (bf16*)(ws + 2*SZ_TAB + 4*SZ_BSH);
  bf16* Wkb = Wqb + (size_t)HID_*HID_;
  bf16* Wvb = Wkb + (size_t)HID_*HID_;
  bf16* Wob = Wvb + (size_t)HID_*HID_;

  k_tables<<<512,256,0,stream>>>(cosT, sinT);
  k_cvt_all<<<dim3(8192,6),256,0,stream>>>(hid, buf1, samat, buf3,
                                           Wq, Wqb, Wk, Wkb, Wv, Wvb, Wo, Wob);
  k_transpose_cvt<<<dim3(32,32,2),256,0,stream>>>(hid, buf2);

  const size_t sBat = (size_t)S_*HID_;  // 4,194,304 elems (== S*S)
  // G1: hm = sum_attn_mask @ hidden + (1-m)*hidden   (batched)
  k_gemm_nt<1><<<dim3(16,16,2),256,0,stream>>>(buf3, buf2, buf4, 2048, sBat, sBat, sBat, 2048, smask, hid);
  // G2: q = hidden_bf @ Wq^T   (M = B*S = 4096)
  k_gemm_nt<0><<<dim3(16,32,1),256,0,stream>>>(buf1, Wqb, buf3, 2048, 0,0,0, 2048, nullptr, nullptr);
  k_rope<<<4096,256,0,stream>>>(buf3, cosT, sinT, pos);
  // G3: k = hm @ Wk^T
  k_gemm_nt<0><<<dim3(16,32,1),256,0,stream>>>(buf4, Wkb, buf2, 2048, 0,0,0, 2048, nullptr, nullptr);
  k_rope<<<4096,256,0,stream>>>(buf2, cosT, sinT, nullptr);
  // G4: v = hm @ Wv^T
  k_gemm_nt<0><<<dim3(16,32,1),256,0,stream>>>(buf4, Wvb, buf1, 2048, 0,0,0, 2048, nullptr, nullptr);
  // attention: O -> buf4 (hm dead)
  k_flash<<<dim3(768),256,0,stream>>>(buf3, buf2, buf1, buf4);
  // G5: out = O @ Wo^T -> fp32
  k_gemm_nt<2><<<dim3(16,32,1),256,0,stream>>>(buf4, Wob, out, 2048, 0,0,0, 2048, nullptr, nullptr);
}